// Round 4
// baseline (1244.558 us; speedup 1.0000x reference)
//
#include <hip/hip_runtime.h>
#include <math.h>

#define BB 128
#define TT 512
#define HH 128
#define G4 512      // 4*H
#define CC 128
#define WW 32

// ---- workspace layout (float slots) ----
#define OFF_FCWT  0                          // 16384
#define OFF_W1P   (OFF_FCWT + CC*HH)         // f16 permuted Whh1: 32768 slots
#define OFF_WI2P  (OFF_W1P  + G4*HH/2)
#define OFF_WH2P  (OFF_WI2P + G4*HH/2)
#define OFF_B1P   (OFF_WH2P + G4*HH/2)       // 512
#define OFF_WI1P  (OFF_B1P + G4)
#define OFF_B2P   (OFF_WI1P + G4)
#define OFF_H2A   (OFF_B2P + G4)             // [T][B][H] fp32 (read-only after k1)
#define OFF_DOLD  (OFF_H2A + TT*BB*HH)
#define OFF_DH    (OFF_DOLD + TT*BB)
#define OFF_MT    (OFF_DH + TT*BB)
#define OFF_ST    (OFF_MT + TT)

typedef _Float16 h2t __attribute__((ext_vector_type(2)));

__device__ __forceinline__ unsigned short f16b(float v) {
    return __builtin_bit_cast(unsigned short, (_Float16)v);
}
__device__ __forceinline__ float dot2f(unsigned int a, unsigned int b, float acc) {
#if defined(__has_builtin) && __has_builtin(__builtin_amdgcn_fdot2)
    return __builtin_amdgcn_fdot2(__builtin_bit_cast(h2t, a),
                                  __builtin_bit_cast(h2t, b), acc, false);
#else
    h2t av = __builtin_bit_cast(h2t, a), bv = __builtin_bit_cast(h2t, b);
    acc = fmaf((float)av.x, (float)bv.x, acc);
    acc = fmaf((float)av.y, (float)bv.y, acc);
    return acc;
#endif
}
__device__ __forceinline__ float rcpf(float x) {
#if defined(__has_builtin) && __has_builtin(__builtin_amdgcn_rcpf)
    return __builtin_amdgcn_rcpf(x);
#else
    return 1.f / x;
#endif
}
// sigma(v) if !isg, tanh(v) = 2*sigma(2v)-1 if isg
__device__ __forceinline__ float act(float v, bool isg) {
    float xin = isg ? v + v : v;
    float r = rcpf(1.f + __expf(-xin));
    return isg ? fmaf(2.f, r, -1.f) : r;
}
// lane-specialized LSTM cell combine within an 8-lane unit group.
// lanes (o = tid&7): 0,1=i  2,3=f  4,5=g  6,7=o ; ag = activated gate.
__device__ __forceinline__ void cellc(float ag, float& creg, float& hn,
                                      bool fsel, bool hsel) {
    float u1 = __shfl_xor(ag, 4);            // i<->g, f<->o
    float pv = fsel ? ag * creg : ag * u1;   // f: sig_f*c ; i: sig_i*tanh_g
    float qv = __shfl_xor(pv, 2);            // i<->f
    float cn = pv + qv;                      // valid on lanes 0..3
    float cb = __shfl_xor(cn, 4);
    cn = hsel ? cb : cn;                     // broadcast to lanes 4..7
    creg = cn;
    hn = ag * act(cn, true);                 // valid on o-lanes (6,7)
}

// 8 dot2 accumulations: one 16-col slice (2 uint4 of f16 weights) x state.
#define DOT8(acc, Wp, hA, hB)                                           \
    acc = dot2f(Wp[0].x, hA.x, acc); acc = dot2f(Wp[0].y, hA.y, acc);   \
    acc = dot2f(Wp[0].z, hA.z, acc); acc = dot2f(Wp[0].w, hA.w, acc);   \
    acc = dot2f(Wp[1].x, hB.x, acc); acc = dot2f(Wp[1].y, hB.y, acc);   \
    acc = dot2f(Wp[1].z, hB.z, acc); acc = dot2f(Wp[1].w, hB.w, acc);

// K0: gate-interleaved (r = h*4 + g) f16 weight images + permuted biases +
// fcW transpose.  (unchanged)
__global__ __launch_bounds__(256) void k0_prep(
    const float* __restrict__ Whh1, const float* __restrict__ Wih2,
    const float* __restrict__ Whh2, const float* __restrict__ fcW,
    const float* __restrict__ Wih1,
    const float* __restrict__ bih1, const float* __restrict__ bhh1,
    const float* __restrict__ bih2, const float* __restrict__ bhh2,
    float* __restrict__ fcWT,
    unsigned short* __restrict__ w1p, unsigned short* __restrict__ wi2p,
    unsigned short* __restrict__ wh2p,
    float* __restrict__ b1p, float* __restrict__ wi1p, float* __restrict__ b2p)
{
    int idx = blockIdx.x * blockDim.x + threadIdx.x;
    if (idx < G4 * HH) {
        int r_old = idx >> 7, k = idx & 127;
        int g = r_old >> 7, h = r_old & 127;
        int dst = (h * 4 + g) * HH + k;
        w1p [dst] = f16b(Whh1[idx]);
        wi2p[dst] = f16b(Wih2[idx]);
        wh2p[dst] = f16b(Whh2[idx]);
    }
    if (idx < CC * HH) {
        int c = idx / HH, h = idx % HH;
        fcWT[h * CC + c] = fcW[idx];
    }
    if (idx < G4) {
        int g = idx >> 7, h = idx & 127;
        int rn = h * 4 + g;
        b1p [rn] = bih1[idx] + bhh1[idx];
        wi1p[rn] = Wih1[idx];
        b2p [rn] = bih2[idx] + bhh2[idx];
    }
}

// K1: LDS-traffic-minimized tiling.  1024 threads; thread = (unit u = tid>>3,
// 16-col slice o = tid&7).  Each thread owns ALL 4 gate-rows of its unit for
// both layers at a 16-col slice -> state re-read is 3 x 32 B = 6 ds_read_b128
// per step (was 24; the LDS read pipe was the measured bottleneck at ~95 B/cy,
// 100% of the ds_read_b128 ceiling).  Gate sums complete in all 8 lanes via a
// 3-level shfl_xor butterfly; cell math stays lane-specialized (lane o handles
// gate (o>>1)&3), so transcendental count is unchanged.
__global__ __launch_bounds__(1024)
__attribute__((amdgpu_waves_per_eu(4, 4)))
void k1_lstm(
    const float* __restrict__ x,
    const float* __restrict__ b1p, const float* __restrict__ wi1p,
    const float* __restrict__ b2p,
    const unsigned short* __restrict__ w1p,
    const unsigned short* __restrict__ wi2p,
    const unsigned short* __restrict__ wh2p,
    float* __restrict__ h2a)
{
    __shared__ __align__(16) unsigned short h1h[2][HH];
    __shared__ __align__(16) unsigned short c1h[2][HH];
    __shared__ __align__(16) unsigned short h2h[2][HH];
    __shared__ float xs[TT];

    const int tid = threadIdx.x;
    const int b   = blockIdx.x;
    const int u8  = tid >> 3;              // hidden unit 0..127
    const int o   = tid & 7;               // col slice: cols [16o, 16o+16)
    const bool s1     = (o & 2) != 0;      // gate-select low bit  (== fsel)
    const bool s2     = (o & 4) != 0;      // gate-select high bit (== hsel)
    const bool isg    = s2 && !s1;         // this lane's role-gate is g (tanh)
    const bool writer = (o == 6);          // one writer lane per unit

    // ---- weights: 4 rows x 16-col slice x 3 matrices -> 24 uint4 = 96 regs
    uint4 w1[4][2], wi2[4][2], wh2[4][2];
    #pragma unroll
    for (int g = 0; g < 4; ++g) {
        const uint4* p1 = (const uint4*)(w1p  + (size_t)(4 * u8 + g) * HH + 16 * o);
        const uint4* p2 = (const uint4*)(wi2p + (size_t)(4 * u8 + g) * HH + 16 * o);
        const uint4* p3 = (const uint4*)(wh2p + (size_t)(4 * u8 + g) * HH + 16 * o);
        w1[g][0] = p1[0];  w1[g][1] = p1[1];
        wi2[g][0] = p2[0]; wi2[g][1] = p2[1];
        wh2[g][0] = p3[0]; wh2[g][1] = p3[1];
    }
    // Pin in registers: opaque to the optimizer -> per-step re-load illegal.
    #pragma unroll
    for (int g = 0; g < 4; ++g) {
        asm volatile("" : "+v"(w1[g][0].x),  "+v"(w1[g][0].y),  "+v"(w1[g][0].z),  "+v"(w1[g][0].w));
        asm volatile("" : "+v"(w1[g][1].x),  "+v"(w1[g][1].y),  "+v"(w1[g][1].z),  "+v"(w1[g][1].w));
        asm volatile("" : "+v"(wi2[g][0].x), "+v"(wi2[g][0].y), "+v"(wi2[g][0].z), "+v"(wi2[g][0].w));
        asm volatile("" : "+v"(wi2[g][1].x), "+v"(wi2[g][1].y), "+v"(wi2[g][1].z), "+v"(wi2[g][1].w));
        asm volatile("" : "+v"(wh2[g][0].x), "+v"(wh2[g][0].y), "+v"(wh2[g][0].z), "+v"(wh2[g][0].w));
        asm volatile("" : "+v"(wh2[g][1].x), "+v"(wh2[g][1].y), "+v"(wh2[g][1].z), "+v"(wh2[g][1].w));
    }
    // per-lane cell scalars for the role-gate (o>>1)&3 of unit u8
    const int rc = 4 * u8 + ((o >> 1) & 3);
    const float wi1v = wi1p[rc];
    const float b1v  = b1p[rc];
    const float b2v  = b2p[rc];

    if (tid < TT) xs[tid] = x[(size_t)b * TT + tid];
    if (tid < HH) {
        h1h[0][tid] = 0; h1h[1][tid] = 0;
        c1h[0][tid] = 0; c1h[1][tid] = 0;
        h2h[0][tid] = 0; h2h[1][tid] = 0;
    }
    float c1reg = 0.f, c2reg = 0.f;
    __syncthreads();

    float* outp = h2a + (size_t)b * HH + u8;

    // ---- prologue u=0: layer-1 only, h1(prev)=0 -> gate is scalar ----
    {
        float ag = act(fmaf(xs[0], wi1v, b1v), isg);
        float hn;
        cellc(ag, c1reg, hn, s1, s2);
        if (writer) { h1h[1][u8] = f16b(hn); c1h[1][u8] = f16b(c1reg); }
    }
    __syncthreads();

    // ---- main: u = 1 .. TT-1 (layer-1 at t=u, layer-2 at t=u-1) ----
    for (int u = 1; u < TT; ++u) {
        const int p = u & 1, q = p ^ 1;
        const float xv = xs[u];

        // ---- phase A: layer-1 (t=u).  h1h[p] = h1(u-1), 32-B slice ----
        {
            const uint4* hp = (const uint4*)&h1h[p][16 * o];
            uint4 hA = hp[0], hB = hp[1];
            float a0 = 0.f, a1 = 0.f, a2 = 0.f, a3 = 0.f;
            DOT8(a0, w1[0], hA, hB)
            DOT8(a1, w1[1], hA, hB)
            DOT8(a2, w1[2], hA, hB)
            DOT8(a3, w1[3], hA, hB)
            // butterfly: every lane gets full sums of all 4 gates
            a0 += __shfl_xor(a0, 1); a0 += __shfl_xor(a0, 2); a0 += __shfl_xor(a0, 4);
            a1 += __shfl_xor(a1, 1); a1 += __shfl_xor(a1, 2); a1 += __shfl_xor(a1, 4);
            a2 += __shfl_xor(a2, 1); a2 += __shfl_xor(a2, 2); a2 += __shfl_xor(a2, 4);
            a3 += __shfl_xor(a3, 1); a3 += __shfl_xor(a3, 2); a3 += __shfl_xor(a3, 4);
            float t0 = s1 ? a1 : a0;
            float t1 = s1 ? a3 : a2;
            float av = s2 ? t1 : t0;                   // a[(o>>1)&3]
            float ag1 = act(av + fmaf(xv, wi1v, b1v), isg);
            float hn;
            cellc(ag1, c1reg, hn, s1, s2);
            if (writer) { h1h[q][u8] = f16b(hn); c1h[q][u8] = f16b(c1reg); }
        }

        // ---- phase B: layer-2 (t=u-1).  c1h[p]=c1(u-1), h2h[p]=h2(u-2) ----
        {
            const uint4* cp = (const uint4*)&c1h[p][16 * o];
            const uint4* gp = (const uint4*)&h2h[p][16 * o];
            uint4 cA = cp[0], cB = cp[1];
            uint4 gA = gp[0], gB = gp[1];
            float d0 = 0.f, d1 = 0.f, d2 = 0.f, d3 = 0.f;
            DOT8(d0, wi2[0], cA, cB)
            DOT8(d1, wi2[1], cA, cB)
            DOT8(d2, wi2[2], cA, cB)
            DOT8(d3, wi2[3], cA, cB)
            DOT8(d0, wh2[0], gA, gB)
            DOT8(d1, wh2[1], gA, gB)
            DOT8(d2, wh2[2], gA, gB)
            DOT8(d3, wh2[3], gA, gB)
            d0 += __shfl_xor(d0, 1); d0 += __shfl_xor(d0, 2); d0 += __shfl_xor(d0, 4);
            d1 += __shfl_xor(d1, 1); d1 += __shfl_xor(d1, 2); d1 += __shfl_xor(d1, 4);
            d2 += __shfl_xor(d2, 1); d2 += __shfl_xor(d2, 2); d2 += __shfl_xor(d2, 4);
            d3 += __shfl_xor(d3, 1); d3 += __shfl_xor(d3, 2); d3 += __shfl_xor(d3, 4);
            float t0 = s1 ? d1 : d0;
            float t1 = s1 ? d3 : d2;
            float dv = s2 ? t1 : t0;
            float ag2 = act(dv + b2v, isg);
            float hn;
            cellc(ag2, c2reg, hn, s1, s2);
            if (writer) {
                h2h[q][u8] = f16b(hn);
                outp[(size_t)(u - 1) * (BB * HH)] = hn;
            }
        }
        __syncthreads();
    }

    // ---- epilogue u=TT: layer-2 only (t = TT-1), buffers p = TT&1 = 0 ----
    {
        const uint4* cp = (const uint4*)&c1h[0][16 * o];
        const uint4* gp = (const uint4*)&h2h[0][16 * o];
        uint4 cA = cp[0], cB = cp[1];
        uint4 gA = gp[0], gB = gp[1];
        float d0 = 0.f, d1 = 0.f, d2 = 0.f, d3 = 0.f;
        DOT8(d0, wi2[0], cA, cB)
        DOT8(d1, wi2[1], cA, cB)
        DOT8(d2, wi2[2], cA, cB)
        DOT8(d3, wi2[3], cA, cB)
        DOT8(d0, wh2[0], gA, gB)
        DOT8(d1, wh2[1], gA, gB)
        DOT8(d2, wh2[2], gA, gB)
        DOT8(d3, wh2[3], gA, gB)
        d0 += __shfl_xor(d0, 1); d0 += __shfl_xor(d0, 2); d0 += __shfl_xor(d0, 4);
        d1 += __shfl_xor(d1, 1); d1 += __shfl_xor(d1, 2); d1 += __shfl_xor(d1, 4);
        d2 += __shfl_xor(d2, 1); d2 += __shfl_xor(d2, 2); d2 += __shfl_xor(d2, 4);
        d3 += __shfl_xor(d3, 1); d3 += __shfl_xor(d3, 2); d3 += __shfl_xor(d3, 4);
        float t0 = s1 ? d1 : d0;
        float t1 = s1 ? d3 : d2;
        float dv = s2 ? t1 : t0;
        float ag2 = act(dv + b2v, isg);
        float hn;
        cellc(ag2, c2reg, hn, s1, s2);
        if (writer) outp[(size_t)(TT - 1) * (BB * HH)] = hn;
    }
}

// K2: d_old[t,b] = h2[t,b,:].wt_old ; d_h[t,b] = h2[t,b,:].wt_h  (unchanged)
__global__ __launch_bounds__(256) void k2_dots(
    const float* __restrict__ h2a, const float* __restrict__ w_t,
    float* __restrict__ dold, float* __restrict__ dh)
{
    const int lane = threadIdx.x & 63;
    const int wave = blockIdx.x * (blockDim.x >> 6) + (threadIdx.x >> 6);
    const int nw = gridDim.x * (blockDim.x >> 6);
    const float wh0 = w_t[lane],       wh1 = w_t[64 + lane];
    const float wo0 = w_t[128 + lane], wo1 = w_t[192 + lane];
    for (int row = wave; row < TT * BB; row += nw) {
        const float* p = h2a + (size_t)row * HH;
        float v0 = p[lane], v1 = p[64 + lane];
        float po = v0 * wo0 + v1 * wo1;
        float ph = v0 * wh0 + v1 * wh1;
        #pragma unroll
        for (int off = 32; off; off >>= 1) {
            po += __shfl_xor(po, off);
            ph += __shfl_xor(ph, off);
        }
        if (lane == 0) { dold[row] = po; dh[row] = ph; }
    }
}

// K3: per-t global softmax stats over valid (j,b): m[t], s[t]  (unchanged)
__global__ __launch_bounds__(256) void k3_stats(
    const float* __restrict__ dold, const float* __restrict__ dh,
    float* __restrict__ mt, float* __restrict__ st)
{
    const int t = blockIdx.x;
    const int tid = threadIdx.x;
    const int cnt = (min(t, WW) + 1) * BB;
    const int jstart = max(t - (WW + 1), -1);

    float m = -INFINITY;
    for (int idx = tid; idx < cnt; idx += 256) {
        int jj = idx >> 7, b = idx & 127;
        int j = jstart + jj;
        float sc = dh[t * BB + b] + (j >= 0 ? dold[j * BB + b] : 0.f);
        m = fmaxf(m, sc);
    }
    #pragma unroll
    for (int off = 32; off; off >>= 1) m = fmaxf(m, __shfl_xor(m, off));
    __shared__ float rbuf[4];
    int wv = tid >> 6, ln = tid & 63;
    if (ln == 0) rbuf[wv] = m;
    __syncthreads();
    m = fmaxf(fmaxf(rbuf[0], rbuf[1]), fmaxf(rbuf[2], rbuf[3]));

    float s = 0.f;
    for (int idx = tid; idx < cnt; idx += 256) {
        int jj = idx >> 7, b = idx & 127;
        int j = jstart + jj;
        float sc = dh[t * BB + b] + (j >= 0 ? dold[j * BB + b] : 0.f);
        s += __expf(sc - m);
    }
    #pragma unroll
    for (int off = 32; off; off >>= 1) s += __shfl_xor(s, off);
    __shared__ float sbuf[4];
    if (ln == 0) sbuf[wv] = s;
    __syncthreads();
    if (tid == 0) { mt[t] = m; st[t] = sbuf[0] + sbuf[1] + sbuf[2] + sbuf[3]; }
}

// K45: fused attention + FC. grid (TT/8, BB), block 256.  (unchanged)
__global__ __launch_bounds__(256) void k45_attn_fc(
    const float* __restrict__ h2a,
    const float* __restrict__ dold, const float* __restrict__ dh,
    const float* __restrict__ mt, const float* __restrict__ st,
    const float* __restrict__ fcWT, const float* __restrict__ fcb,
    float* __restrict__ out)
{
    const int t0 = blockIdx.x * 8;
    const int b  = blockIdx.y;
    const int tid = threadIdx.x;

    __shared__ float hbuf[41][HH];     // rows t0-33 .. t0+7
    __shared__ float wjs[8][36];
    __shared__ float ytile[8][HH];

    for (int i = tid; i < 41 * 32; i += 256) {
        int r = i >> 5, q4 = i & 31;
        int t = t0 - 33 + r;
        float4 v = make_float4(0.f, 0.f, 0.f, 0.f);
        if (t >= 0)
            v = *(const float4*)(h2a + (size_t)t * (BB * HH) + (size_t)b * HH + q4 * 4);
        *(float4*)&hbuf[r][q4 * 4] = v;
    }
    for (int i = tid; i < 8 * 33; i += 256) {
        int tt = i / 33, ss = i % 33;
        int t = t0 + tt, j = t - 33 + ss;
        float w = 0.f;
        if (j >= 0)
            w = __expf(dold[j * BB + b] + dh[t * BB + b] - mt[t]) / st[t];
        wjs[tt][ss] = w;
    }
    __syncthreads();

    {
        const int tq = tid >> 5;
        const int hq = (tid & 31) * 4;
        float4 acc = *(const float4*)&hbuf[tq + 33][hq];   // h2[t]
        #pragma unroll 11
        for (int ss = 0; ss < 33; ++ss) {
            float w = wjs[tq][ss];
            float4 hb = *(const float4*)&hbuf[tq + ss][hq];
            acc.x = fmaf(w, hb.x, acc.x);
            acc.y = fmaf(w, hb.y, acc.y);
            acc.z = fmaf(w, hb.z, acc.z);
            acc.w = fmaf(w, hb.w, acc.w);
        }
        *(float4*)&ytile[tq][hq] = acc;
    }
    __syncthreads();

    {
        const int c  = tid & 127;
        const int th = tid >> 7;
        float acc[4];
        const float bias = fcb[c];
        #pragma unroll
        for (int i = 0; i < 4; ++i) acc[i] = bias;
        for (int hh = 0; hh < HH; ++hh) {
            float w = fcWT[hh * CC + c];
            #pragma unroll
            for (int i = 0; i < 4; ++i)
                acc[i] = fmaf(ytile[th * 4 + i][hh], w, acc[i]);
        }
        #pragma unroll
        for (int i = 0; i < 4; ++i) {
            int t = t0 + th * 4 + i;
            out[(size_t)b * (TT * CC) + (size_t)t * CC + c] = acc[i];
        }
    }
}

extern "C" void kernel_launch(void* const* d_in, const int* in_sizes, int n_in,
                              void* d_out, int out_size, void* d_ws, size_t ws_size,
                              hipStream_t stream)
{
    const float* x    = (const float*)d_in[0];
    const float* Wih1 = (const float*)d_in[1];
    const float* Whh1 = (const float*)d_in[2];
    const float* bih1 = (const float*)d_in[3];
    const float* bhh1 = (const float*)d_in[4];
    const float* Wih2 = (const float*)d_in[5];
    const float* Whh2 = (const float*)d_in[6];
    const float* bih2 = (const float*)d_in[7];
    const float* bhh2 = (const float*)d_in[8];
    const float* w_t  = (const float*)d_in[9];
    const float* fcW  = (const float*)d_in[10];
    const float* fcb  = (const float*)d_in[11];
    float* out = (float*)d_out;

    float* ws   = (float*)d_ws;
    float* fcWT = ws + OFF_FCWT;
    unsigned short* w1p  = (unsigned short*)(ws + OFF_W1P);
    unsigned short* wi2p = (unsigned short*)(ws + OFF_WI2P);
    unsigned short* wh2p = (unsigned short*)(ws + OFF_WH2P);
    float* b1pp = ws + OFF_B1P;
    float* wi1p = ws + OFF_WI1P;
    float* b2pp = ws + OFF_B2P;
    float* h2a  = ws + OFF_H2A;
    float* dold = ws + OFF_DOLD;
    float* dh   = ws + OFF_DH;
    float* mt   = ws + OFF_MT;
    float* st   = ws + OFF_ST;

    k0_prep<<<dim3((G4 * HH + 255) / 256), dim3(256), 0, stream>>>(
        Whh1, Wih2, Whh2, fcW, Wih1, bih1, bhh1, bih2, bhh2,
        fcWT, w1p, wi2p, wh2p, b1pp, wi1p, b2pp);

    k1_lstm<<<dim3(BB), dim3(1024), 0, stream>>>(
        x, b1pp, wi1p, b2pp, w1p, wi2p, wh2p, h2a);

    k2_dots<<<dim3(256), dim3(256), 0, stream>>>(h2a, w_t, dold, dh);

    k3_stats<<<dim3(TT), dim3(256), 0, stream>>>(dold, dh, mt, st);

    k45_attn_fc<<<dim3(TT / 8, BB), dim3(256), 0, stream>>>(
        h2a, dold, dh, mt, st, fcWT, fcb, out);
}

// Round 5
// 1056.933 us; speedup vs baseline: 1.1775x; 1.1775x over previous
//
#include <hip/hip_runtime.h>
#include <math.h>

#define BB 128
#define TT 512
#define HH 128
#define G4 512      // 4*H
#define CC 128
#define WW 32

// ---- workspace layout (float slots) ----
#define OFF_FCWT  0                          // 16384
#define OFF_W1P   (OFF_FCWT + CC*HH)         // f16 permuted Whh1: 32768 slots
#define OFF_WI2P  (OFF_W1P  + G4*HH/2)
#define OFF_WH2P  (OFF_WI2P + G4*HH/2)
#define OFF_B1P   (OFF_WH2P + G4*HH/2)       // 512
#define OFF_WI1P  (OFF_B1P + G4)
#define OFF_B2P   (OFF_WI1P + G4)
#define OFF_H2A   (OFF_B2P + G4)             // [T][B][H] fp32 (read-only after k1)
#define OFF_DOLD  (OFF_H2A + TT*BB*HH)
#define OFF_DH    (OFF_DOLD + TT*BB)
#define OFF_MT    (OFF_DH + TT*BB)
#define OFF_ST    (OFF_MT + TT)

typedef _Float16 h2t __attribute__((ext_vector_type(2)));

__device__ __forceinline__ unsigned short f16b(float v) {
    return __builtin_bit_cast(unsigned short, (_Float16)v);
}
__device__ __forceinline__ float dot2f(unsigned int a, unsigned int b, float acc) {
#if defined(__has_builtin) && __has_builtin(__builtin_amdgcn_fdot2)
    return __builtin_amdgcn_fdot2(__builtin_bit_cast(h2t, a),
                                  __builtin_bit_cast(h2t, b), acc, false);
#else
    h2t av = __builtin_bit_cast(h2t, a), bv = __builtin_bit_cast(h2t, b);
    acc = fmaf((float)av.x, (float)bv.x, acc);
    acc = fmaf((float)av.y, (float)bv.y, acc);
    return acc;
#endif
}
__device__ __forceinline__ float rcpf(float x) {
#if defined(__has_builtin) && __has_builtin(__builtin_amdgcn_rcpf)
    return __builtin_amdgcn_rcpf(x);
#else
    return 1.f / x;
#endif
}
// sigma(v) if !isg, tanh(v) = 2*sigma(2v)-1 if isg
__device__ __forceinline__ float act(float v, bool isg) {
    float xin = isg ? v + v : v;
    float r = rcpf(1.f + __expf(-xin));
    return isg ? fmaf(2.f, r, -1.f) : r;
}

// quad reduce via DPP quad_perm (pure VALU, no DS-pipe traffic).
// xor1 = quad_perm[1,0,3,2] = 0xB1 ; xor2 = quad_perm[2,3,0,1] = 0x4E.
template <int CTRL>
__device__ __forceinline__ float dppadd(float v) {
#if defined(__has_builtin) && __has_builtin(__builtin_amdgcn_update_dpp)
    int m = __builtin_amdgcn_update_dpp(0, __builtin_bit_cast(int, v),
                                        CTRL, 0xf, 0xf, true);
    return v + __builtin_bit_cast(float, m);
#else
    return v + __shfl_xor(v, CTRL == 0xB1 ? 1 : 2);
#endif
}
__device__ __forceinline__ float qred(float v) {
    v = dppadd<0xB1>(v);
    v = dppadd<0x4E>(v);
    return v;
}

// 16 dot2: one 32-col row-slice (4 uint4 of f16 weights) x state (4 uint4)
#define DOT16(acc, W, v0, v1, v2, v3)                                   \
    acc = dot2f(W[0].x, v0.x, acc); acc = dot2f(W[0].y, v0.y, acc);     \
    acc = dot2f(W[0].z, v0.z, acc); acc = dot2f(W[0].w, v0.w, acc);     \
    acc = dot2f(W[1].x, v1.x, acc); acc = dot2f(W[1].y, v1.y, acc);     \
    acc = dot2f(W[1].z, v1.z, acc); acc = dot2f(W[1].w, v1.w, acc);     \
    acc = dot2f(W[2].x, v2.x, acc); acc = dot2f(W[2].y, v2.y, acc);     \
    acc = dot2f(W[2].z, v2.z, acc); acc = dot2f(W[2].w, v2.w, acc);     \
    acc = dot2f(W[3].x, v3.x, acc); acc = dot2f(W[3].y, v3.y, acc);     \
    acc = dot2f(W[3].z, v3.z, acc); acc = dot2f(W[3].w, v3.w, acc);

// LDS-visibility barrier WITHOUT vmcnt drain: the per-step h2a global store
// is allowed to stay in flight across the barrier (nothing reads h2a until
// k1 completes).  __syncthreads would wait vmcnt(0) every step.
#define STEP_BARRIER() asm volatile("s_waitcnt lgkmcnt(0)\n\ts_barrier" ::: "memory")

// K0: gate-interleaved (r = h*4 + g) f16 weight images + permuted biases +
// fcW transpose.  (unchanged)
__global__ __launch_bounds__(256) void k0_prep(
    const float* __restrict__ Whh1, const float* __restrict__ Wih2,
    const float* __restrict__ Whh2, const float* __restrict__ fcW,
    const float* __restrict__ Wih1,
    const float* __restrict__ bih1, const float* __restrict__ bhh1,
    const float* __restrict__ bih2, const float* __restrict__ bhh2,
    float* __restrict__ fcWT,
    unsigned short* __restrict__ w1p, unsigned short* __restrict__ wi2p,
    unsigned short* __restrict__ wh2p,
    float* __restrict__ b1p, float* __restrict__ wi1p, float* __restrict__ b2p)
{
    int idx = blockIdx.x * blockDim.x + threadIdx.x;
    if (idx < G4 * HH) {
        int r_old = idx >> 7, k = idx & 127;
        int g = r_old >> 7, h = r_old & 127;
        int dst = (h * 4 + g) * HH + k;
        w1p [dst] = f16b(Whh1[idx]);
        wi2p[dst] = f16b(Wih2[idx]);
        wh2p[dst] = f16b(Whh2[idx]);
    }
    if (idx < CC * HH) {
        int c = idx / HH, h = idx % HH;
        fcWT[h * CC + c] = fcW[idx];
    }
    if (idx < G4) {
        int g = idx >> 7, h = idx & 127;
        int rn = h * 4 + g;
        b1p [rn] = bih1[idx] + bhh1[idx];
        wi1p[rn] = Wih1[idx];
        b2p [rn] = bih2[idx] + bhh2[idx];
    }
}

// K1: DS-pipe-minimized step.  1024 threads; thread = (unit h = tid>>3,
// half = (tid>>2)&1, col slice s = tid&3).  Each thread owns 2 adjacent
// gate-rows (half=0: i,f ; half=1: g,o) x 32 cols for all 3 matrices
// (96 weight dwords).  Per step per thread: 12 ds_read_b128 (half of R1),
// gate reduce entirely in DPP quad_perm (zero DS ops, was 16 swizzles),
// cell combine via 2 xor-4 shuffles per cell (lane pair tid^4), barrier
// without vmcnt drain.  The per-CU DS pipe was the measured ~4150cy/step
// bottleneck; this roughly halves it.
__global__ __launch_bounds__(1024) void k1_lstm(
    const float* __restrict__ x,
    const float* __restrict__ b1p, const float* __restrict__ wi1p,
    const float* __restrict__ b2p,
    const unsigned short* __restrict__ w1p,
    const unsigned short* __restrict__ wi2p,
    const unsigned short* __restrict__ wh2p,
    float* __restrict__ h2a)
{
    __shared__ __align__(16) unsigned short h1h[2][HH];
    __shared__ __align__(16) unsigned short c1h[2][HH];
    __shared__ __align__(16) unsigned short h2h[2][HH];
    __shared__ float xs[TT];

    const int tid  = threadIdx.x;
    const int b    = blockIdx.x;
    const int s    = tid & 3;            // 32-col slice
    const int half = (tid >> 2) & 1;     // 0: rows (i,f) ; 1: rows (g,o)
    const int h    = tid >> 3;           // hidden unit 0..127
    const int gr0  = 4 * h + 2 * half;   // first owned gate-row
    const bool hB  = (half != 0);

    // ---- weights: 2 rows x 32-col slice x 3 matrices -> 24 uint4 = 96 dw
    uint4 w1[2][4], wi2[2][4], wh2[2][4];
    #pragma unroll
    for (int rr = 0; rr < 2; ++rr) {
        const uint4* p1 = (const uint4*)(w1p  + (size_t)(gr0 + rr) * HH + 32 * s);
        const uint4* p2 = (const uint4*)(wi2p + (size_t)(gr0 + rr) * HH + 32 * s);
        const uint4* p3 = (const uint4*)(wh2p + (size_t)(gr0 + rr) * HH + 32 * s);
        #pragma unroll
        for (int k = 0; k < 4; ++k) {
            w1[rr][k] = p1[k]; wi2[rr][k] = p2[k]; wh2[rr][k] = p3[k];
        }
    }
    const float wi1v0 = wi1p[gr0],     b1v0 = b1p[gr0],     b2v0 = b2p[gr0];
    const float wi1v1 = wi1p[gr0 + 1], b1v1 = b1p[gr0 + 1], b2v1 = b2p[gr0 + 1];

    if (tid < TT) xs[tid] = x[(size_t)b * TT + tid];
    if (tid < HH) {
        h1h[0][tid] = 0; h1h[1][tid] = 0;
        c1h[0][tid] = 0; c1h[1][tid] = 0;
        h2h[0][tid] = 0; h2h[1][tid] = 0;
    }
    float c1reg = 0.f, c2reg = 0.f;   // cell state lives on half==0 threads
    __syncthreads();

    float* outp = h2a + (size_t)b * HH + h;

    // ---- prologue u=0: layer-1 only, h1(prev)=0 -> gates are scalar ----
    {
        float g0 = fmaf(xs[0], wi1v0, b1v0);
        float g1 = fmaf(xs[0], wi1v1, b1v1);
        float e0 = act(g0, hB);                 // A: sig(i) ; B: tanh(g)
        float e1 = act(g1, false);              // A: sig(f) ; B: sig(o)
        float peer = __shfl_xor(e0, 4);         // A <- tanh(g)
        float cn = e1 * c1reg + e0 * peer;      // valid on A
        c1reg = hB ? c1reg : cn;
        float cnp = __shfl_xor(cn, 4);          // B <- cn
        float hn1 = e1 * act(cnp, true);        // valid on B: sig(o)*tanh(cn)
        if (s == 0) {
            if (hB) h1h[1][h] = f16b(hn1);
            else    c1h[1][h] = f16b(cn);
        }
    }
    STEP_BARRIER();

    // ---- main: u = 1 .. TT-1 (layer-1 at t=u, layer-2 at t=u-1) ----
    for (int u = 1; u < TT; ++u) {
        const int p = u & 1, q = p ^ 1;
        const float xv = xs[u];

        const uint4* hp = (const uint4*)&h1h[p][32 * s];
        const uint4* cp = (const uint4*)&c1h[p][32 * s];
        const uint4* gp = (const uint4*)&h2h[p][32 * s];

        uint4 hv0 = hp[0], hv1 = hp[1], hv2 = hp[2], hv3 = hp[3];
        float a0 = 0.f, a1 = 0.f;
        DOT16(a0, w1[0], hv0, hv1, hv2, hv3)
        DOT16(a1, w1[1], hv0, hv1, hv2, hv3)

        uint4 cv0 = cp[0], cv1 = cp[1], cv2 = cp[2], cv3 = cp[3];
        uint4 gv0 = gp[0], gv1 = gp[1], gv2 = gp[2], gv3 = gp[3];
        float d0 = 0.f, d1 = 0.f;
        DOT16(d0, wi2[0], cv0, cv1, cv2, cv3)
        DOT16(d0, wh2[0], gv0, gv1, gv2, gv3)
        DOT16(d1, wi2[1], cv0, cv1, cv2, cv3)
        DOT16(d1, wh2[1], gv0, gv1, gv2, gv3)

        // quad reduce (pure DPP, no LDS)
        a0 = qred(a0); a1 = qred(a1);
        d0 = qred(d0); d1 = qred(d1);

        // ---- cell-1 (t=u) ----
        float g0 = a0 + fmaf(xv, wi1v0, b1v0);
        float g1 = a1 + fmaf(xv, wi1v1, b1v1);
        float e0 = act(g0, hB);
        float e1 = act(g1, false);
        float peer = __shfl_xor(e0, 4);
        float cn1 = e1 * c1reg + e0 * peer;
        c1reg = hB ? c1reg : cn1;
        float cnp1 = __shfl_xor(cn1, 4);
        float hn1 = e1 * act(cnp1, true);

        // ---- cell-2 (t=u-1) ----
        float f0 = d0 + b2v0;
        float f1 = d1 + b2v1;
        float u0 = act(f0, hB);
        float u1 = act(f1, false);
        float peer2 = __shfl_xor(u0, 4);
        float cn2 = u1 * c2reg + u0 * peer2;
        c2reg = hB ? c2reg : cn2;
        float cnp2 = __shfl_xor(cn2, 4);
        float hn2 = u1 * act(cnp2, true);

        if (s == 0) {
            if (hB) {
                h1h[q][h] = f16b(hn1);
                h2h[q][h] = f16b(hn2);
                outp[(size_t)(u - 1) * (BB * HH)] = hn2;
            } else {
                c1h[q][h] = f16b(cn1);
            }
        }
        STEP_BARRIER();
    }

    // ---- epilogue u=TT: layer-2 only (t = TT-1), buffers p = TT&1 = 0 ----
    {
        const uint4* cp = (const uint4*)&c1h[0][32 * s];
        const uint4* gp = (const uint4*)&h2h[0][32 * s];
        uint4 cv0 = cp[0], cv1 = cp[1], cv2 = cp[2], cv3 = cp[3];
        uint4 gv0 = gp[0], gv1 = gp[1], gv2 = gp[2], gv3 = gp[3];
        float d0 = 0.f, d1 = 0.f;
        DOT16(d0, wi2[0], cv0, cv1, cv2, cv3)
        DOT16(d0, wh2[0], gv0, gv1, gv2, gv3)
        DOT16(d1, wi2[1], cv0, cv1, cv2, cv3)
        DOT16(d1, wh2[1], gv0, gv1, gv2, gv3)
        d0 = qred(d0); d1 = qred(d1);
        float f0 = d0 + b2v0;
        float f1 = d1 + b2v1;
        float u0 = act(f0, hB);
        float u1 = act(f1, false);
        float peer2 = __shfl_xor(u0, 4);
        float cn2 = u1 * c2reg + u0 * peer2;
        float cnp2 = __shfl_xor(cn2, 4);
        float hn2 = u1 * act(cnp2, true);
        if (hB && s == 0) outp[(size_t)(TT - 1) * (BB * HH)] = hn2;
    }
}

// K2: d_old[t,b] = h2[t,b,:].wt_old ; d_h[t,b] = h2[t,b,:].wt_h  (unchanged)
__global__ __launch_bounds__(256) void k2_dots(
    const float* __restrict__ h2a, const float* __restrict__ w_t,
    float* __restrict__ dold, float* __restrict__ dh)
{
    const int lane = threadIdx.x & 63;
    const int wave = blockIdx.x * (blockDim.x >> 6) + (threadIdx.x >> 6);
    const int nw = gridDim.x * (blockDim.x >> 6);
    const float wh0 = w_t[lane],       wh1 = w_t[64 + lane];
    const float wo0 = w_t[128 + lane], wo1 = w_t[192 + lane];
    for (int row = wave; row < TT * BB; row += nw) {
        const float* p = h2a + (size_t)row * HH;
        float v0 = p[lane], v1 = p[64 + lane];
        float po = v0 * wo0 + v1 * wo1;
        float ph = v0 * wh0 + v1 * wh1;
        #pragma unroll
        for (int off = 32; off; off >>= 1) {
            po += __shfl_xor(po, off);
            ph += __shfl_xor(ph, off);
        }
        if (lane == 0) { dold[row] = po; dh[row] = ph; }
    }
}

// K3: per-t global softmax stats over valid (j,b): m[t], s[t]  (unchanged)
__global__ __launch_bounds__(256) void k3_stats(
    const float* __restrict__ dold, const float* __restrict__ dh,
    float* __restrict__ mt, float* __restrict__ st)
{
    const int t = blockIdx.x;
    const int tid = threadIdx.x;
    const int cnt = (min(t, WW) + 1) * BB;
    const int jstart = max(t - (WW + 1), -1);

    float m = -INFINITY;
    for (int idx = tid; idx < cnt; idx += 256) {
        int jj = idx >> 7, b = idx & 127;
        int j = jstart + jj;
        float sc = dh[t * BB + b] + (j >= 0 ? dold[j * BB + b] : 0.f);
        m = fmaxf(m, sc);
    }
    #pragma unroll
    for (int off = 32; off; off >>= 1) m = fmaxf(m, __shfl_xor(m, off));
    __shared__ float rbuf[4];
    int wv = tid >> 6, ln = tid & 63;
    if (ln == 0) rbuf[wv] = m;
    __syncthreads();
    m = fmaxf(fmaxf(rbuf[0], rbuf[1]), fmaxf(rbuf[2], rbuf[3]));

    float s = 0.f;
    for (int idx = tid; idx < cnt; idx += 256) {
        int jj = idx >> 7, b = idx & 127;
        int j = jstart + jj;
        float sc = dh[t * BB + b] + (j >= 0 ? dold[j * BB + b] : 0.f);
        s += __expf(sc - m);
    }
    #pragma unroll
    for (int off = 32; off; off >>= 1) s += __shfl_xor(s, off);
    __shared__ float sbuf[4];
    if (ln == 0) sbuf[wv] = s;
    __syncthreads();
    if (tid == 0) { mt[t] = m; st[t] = sbuf[0] + sbuf[1] + sbuf[2] + sbuf[3]; }
}

// K45: fused attention + FC. grid (TT/8, BB), block 256.  (unchanged)
__global__ __launch_bounds__(256) void k45_attn_fc(
    const float* __restrict__ h2a,
    const float* __restrict__ dold, const float* __restrict__ dh,
    const float* __restrict__ mt, const float* __restrict__ st,
    const float* __restrict__ fcWT, const float* __restrict__ fcb,
    float* __restrict__ out)
{
    const int t0 = blockIdx.x * 8;
    const int b  = blockIdx.y;
    const int tid = threadIdx.x;

    __shared__ float hbuf[41][HH];     // rows t0-33 .. t0+7
    __shared__ float wjs[8][36];
    __shared__ float ytile[8][HH];

    for (int i = tid; i < 41 * 32; i += 256) {
        int r = i >> 5, q4 = i & 31;
        int t = t0 - 33 + r;
        float4 v = make_float4(0.f, 0.f, 0.f, 0.f);
        if (t >= 0)
            v = *(const float4*)(h2a + (size_t)t * (BB * HH) + (size_t)b * HH + q4 * 4);
        *(float4*)&hbuf[r][q4 * 4] = v;
    }
    for (int i = tid; i < 8 * 33; i += 256) {
        int tt = i / 33, ss = i % 33;
        int t = t0 + tt, j = t - 33 + ss;
        float w = 0.f;
        if (j >= 0)
            w = __expf(dold[j * BB + b] + dh[t * BB + b] - mt[t]) / st[t];
        wjs[tt][ss] = w;
    }
    __syncthreads();

    {
        const int tq = tid >> 5;
        const int hq = (tid & 31) * 4;
        float4 acc = *(const float4*)&hbuf[tq + 33][hq];   // h2[t]
        #pragma unroll 11
        for (int ss = 0; ss < 33; ++ss) {
            float w = wjs[tq][ss];
            float4 hb = *(const float4*)&hbuf[tq + ss][hq];
            acc.x = fmaf(w, hb.x, acc.x);
            acc.y = fmaf(w, hb.y, acc.y);
            acc.z = fmaf(w, hb.z, acc.z);
            acc.w = fmaf(w, hb.w, acc.w);
        }
        *(float4*)&ytile[tq][hq] = acc;
    }
    __syncthreads();

    {
        const int c  = tid & 127;
        const int th = tid >> 7;
        float acc[4];
        const float bias = fcb[c];
        #pragma unroll
        for (int i = 0; i < 4; ++i) acc[i] = bias;
        for (int hh = 0; hh < HH; ++hh) {
            float w = fcWT[hh * CC + c];
            #pragma unroll
            for (int i = 0; i < 4; ++i)
                acc[i] = fmaf(ytile[th * 4 + i][hh], w, acc[i]);
        }
        #pragma unroll
        for (int i = 0; i < 4; ++i) {
            int t = t0 + th * 4 + i;
            out[(size_t)b * (TT * CC) + (size_t)t * CC + c] = acc[i];
        }
    }
}

extern "C" void kernel_launch(void* const* d_in, const int* in_sizes, int n_in,
                              void* d_out, int out_size, void* d_ws, size_t ws_size,
                              hipStream_t stream)
{
    const float* x    = (const float*)d_in[0];
    const float* Wih1 = (const float*)d_in[1];
    const float* Whh1 = (const float*)d_in[2];
    const float* bih1 = (const float*)d_in[3];
    const float* bhh1 = (const float*)d_in[4];
    const float* Wih2 = (const float*)d_in[5];
    const float* Whh2 = (const float*)d_in[6];
    const float* bih2 = (const float*)d_in[7];
    const float* bhh2 = (const float*)d_in[8];
    const float* w_t  = (const float*)d_in[9];
    const float* fcW  = (const float*)d_in[10];
    const float* fcb  = (const float*)d_in[11];
    float* out = (float*)d_out;

    float* ws   = (float*)d_ws;
    float* fcWT = ws + OFF_FCWT;
    unsigned short* w1p  = (unsigned short*)(ws + OFF_W1P);
    unsigned short* wi2p = (unsigned short*)(ws + OFF_WI2P);
    unsigned short* wh2p = (unsigned short*)(ws + OFF_WH2P);
    float* b1pp = ws + OFF_B1P;
    float* wi1p = ws + OFF_WI1P;
    float* b2pp = ws + OFF_B2P;
    float* h2a  = ws + OFF_H2A;
    float* dold = ws + OFF_DOLD;
    float* dh   = ws + OFF_DH;
    float* mt   = ws + OFF_MT;
    float* st   = ws + OFF_ST;

    k0_prep<<<dim3((G4 * HH + 255) / 256), dim3(256), 0, stream>>>(
        Whh1, Wih2, Whh2, fcW, Wih1, bih1, bhh1, bih2, bhh2,
        fcWT, w1p, wi2p, wh2p, b1pp, wi1p, b2pp);

    k1_lstm<<<dim3(BB), dim3(1024), 0, stream>>>(
        x, b1pp, wi1p, b2pp, w1p, wi2p, wh2p, h2a);

    k2_dots<<<dim3(256), dim3(256), 0, stream>>>(h2a, w_t, dold, dh);

    k3_stats<<<dim3(TT), dim3(256), 0, stream>>>(dold, dh, mt, st);

    k45_attn_fc<<<dim3(TT / 8, BB), dim3(256), 0, stream>>>(
        h2a, dold, dh, mt, st, fcWT, fcb, out);
}

// Round 6
// 881.114 us; speedup vs baseline: 1.4125x; 1.1995x over previous
//
#include <hip/hip_runtime.h>
#include <math.h>

#define BB 128
#define TT 512
#define HH 128
#define G4 512      // 4*H
#define CC 128
#define WW 32

// ---- workspace layout (float slots) ----
#define OFF_FCWT  0                          // 16384
#define OFF_W1P   (OFF_FCWT + CC*HH)         // f16 permuted Whh1: 32768 slots
#define OFF_WI2P  (OFF_W1P  + G4*HH/2)
#define OFF_WH2P  (OFF_WI2P + G4*HH/2)
#define OFF_B1P   (OFF_WH2P + G4*HH/2)       // 512
#define OFF_WI1P  (OFF_B1P + G4)
#define OFF_B2P   (OFF_WI1P + G4)
#define OFF_H2A   (OFF_B2P + G4)             // [T][B][H] fp32 (read-only after k1)
#define OFF_DOLD  (OFF_H2A + TT*BB*HH)
#define OFF_DH    (OFF_DOLD + TT*BB)
#define OFF_MT    (OFF_DH + TT*BB)
#define OFF_ST    (OFF_MT + TT)

typedef _Float16 h2t __attribute__((ext_vector_type(2)));

__device__ __forceinline__ unsigned short f16b(float v) {
    return __builtin_bit_cast(unsigned short, (_Float16)v);
}
__device__ __forceinline__ float dot2f(unsigned int a, unsigned int b, float acc) {
#if defined(__has_builtin) && __has_builtin(__builtin_amdgcn_fdot2)
    return __builtin_amdgcn_fdot2(__builtin_bit_cast(h2t, a),
                                  __builtin_bit_cast(h2t, b), acc, false);
#else
    h2t av = __builtin_bit_cast(h2t, a), bv = __builtin_bit_cast(h2t, b);
    acc = fmaf((float)av.x, (float)bv.x, acc);
    acc = fmaf((float)av.y, (float)bv.y, acc);
    return acc;
#endif
}
__device__ __forceinline__ float rcpf(float x) {
#if defined(__has_builtin) && __has_builtin(__builtin_amdgcn_rcpf)
    return __builtin_amdgcn_rcpf(x);
#else
    return 1.f / x;
#endif
}
// sigma(v) if !isg, tanh(v) = 2*sigma(2v)-1 if isg
__device__ __forceinline__ float act(float v, bool isg) {
    float xin = isg ? v + v : v;
    float r = rcpf(1.f + __expf(-xin));
    return isg ? fmaf(2.f, r, -1.f) : r;
}

// DPP quad_perm helpers (pure VALU, quad-local, no DS-pipe traffic).
// xor1 = quad_perm[1,0,3,2] = 0xB1 ; xor2 = quad_perm[2,3,0,1] = 0x4E.
template <int CTRL>
__device__ __forceinline__ float dppadd(float v) {
#if defined(__has_builtin) && __has_builtin(__builtin_amdgcn_update_dpp)
    int m = __builtin_amdgcn_update_dpp(0, __builtin_bit_cast(int, v),
                                        CTRL, 0xf, 0xf, true);
    return v + __builtin_bit_cast(float, m);
#else
    return v + __shfl_xor(v, CTRL == 0xB1 ? 1 : 2);
#endif
}
template <int CTRL>
__device__ __forceinline__ float dppmov(float v) {
#if defined(__has_builtin) && __has_builtin(__builtin_amdgcn_update_dpp)
    int m = __builtin_amdgcn_update_dpp(0, __builtin_bit_cast(int, v),
                                        CTRL, 0xf, 0xf, true);
    return __builtin_bit_cast(float, m);
#else
    return __shfl_xor(v, CTRL == 0xB1 ? 1 : 2);
#endif
}

// 32 dot2: one 64-col row-slice (8 uint4 f16 weights) x state (8 uint4)
__device__ __forceinline__ void dot32(float& acc, const uint4* W, const uint4* S) {
    #pragma unroll
    for (int k = 0; k < 8; ++k) {
        acc = dot2f(W[k].x, S[k].x, acc);
        acc = dot2f(W[k].y, S[k].y, acc);
        acc = dot2f(W[k].z, S[k].z, acc);
        acc = dot2f(W[k].w, S[k].w, acc);
    }
}

// LDS-visibility barrier WITHOUT vmcnt drain (per-step h2a store stays in
// flight; nothing reads h2a until k1 completes).
#define STEP_BARRIER() asm volatile("s_waitcnt lgkmcnt(0)\n\ts_barrier" ::: "memory")

// K0: gate-interleaved (r = h*4 + g) f16 weight images + permuted biases +
// fcW transpose.  (unchanged)
__global__ __launch_bounds__(256) void k0_prep(
    const float* __restrict__ Whh1, const float* __restrict__ Wih2,
    const float* __restrict__ Whh2, const float* __restrict__ fcW,
    const float* __restrict__ Wih1,
    const float* __restrict__ bih1, const float* __restrict__ bhh1,
    const float* __restrict__ bih2, const float* __restrict__ bhh2,
    float* __restrict__ fcWT,
    unsigned short* __restrict__ w1p, unsigned short* __restrict__ wi2p,
    unsigned short* __restrict__ wh2p,
    float* __restrict__ b1p, float* __restrict__ wi1p, float* __restrict__ b2p)
{
    int idx = blockIdx.x * blockDim.x + threadIdx.x;
    if (idx < G4 * HH) {
        int r_old = idx >> 7, k = idx & 127;
        int g = r_old >> 7, h = r_old & 127;
        int dst = (h * 4 + g) * HH + k;
        w1p [dst] = f16b(Whh1[idx]);
        wi2p[dst] = f16b(Wih2[idx]);
        wh2p[dst] = f16b(Whh2[idx]);
    }
    if (idx < CC * HH) {
        int c = idx / HH, h = idx % HH;
        fcWT[h * CC + c] = fcW[idx];
    }
    if (idx < G4) {
        int g = idx >> 7, h = idx & 127;
        int rn = h * 4 + g;
        b1p [rn] = bih1[idx] + bhh1[idx];
        wi1p[rn] = Wih1[idx];
        b2p [rn] = bih2[idx] + bhh2[idx];
    }
}

// K1: TRUE register-resident weights.  512 threads/block; thread =
// (unit h = tid>>2, row-pair half = (tid>>1)&1, col half s = tid&1).
// Per thread: 2 gate-rows x 64 cols x 3 matrices = 192 weight dwords.
// amdgpu_waves_per_eu(2,2) -> 256-VGPR budget (2 waves/SIMD): 192 weights +
// 32 state + ~20 temps ~= 245 <= 256, so for the FIRST time the weights can
// stay in VGPRs (every prior round: live set > cap -> forced spill -> 384
// KB/step/CU L2 re-stream ~= 4200 cy = the measured step time, invariant
// across 5 structural variants).  All cross-lane ops are quad-local DPP
// (col reduce = xor1 add, cell combine = xor2 mov): zero DS shuffles.
// State reads: 6 ds_read_b128/thread/step.
__global__ __launch_bounds__(512)
__attribute__((amdgpu_waves_per_eu(2, 2)))
void k1_lstm(
    const float* __restrict__ x,
    const float* __restrict__ b1p, const float* __restrict__ wi1p,
    const float* __restrict__ b2p,
    const unsigned short* __restrict__ w1p,
    const unsigned short* __restrict__ wi2p,
    const unsigned short* __restrict__ wh2p,
    float* __restrict__ h2a)
{
    __shared__ __align__(16) unsigned short h1h[2][HH];
    __shared__ __align__(16) unsigned short c1h[2][HH];
    __shared__ __align__(16) unsigned short h2h[2][HH];
    __shared__ float xs[TT];

    const int tid  = threadIdx.x;
    const int b    = blockIdx.x;
    const int s    = tid & 1;            // col half: cols [64s, 64s+64)
    const int half = (tid >> 1) & 1;     // 0: rows (i,f) ; 1: rows (g,o)
    const int h    = tid >> 2;           // hidden unit 0..127
    const int gr0  = 4 * h + 2 * half;   // first owned gate-row
    const bool hB  = (half != 0);

    // ---- weights: 2 rows x 64-col half x 3 matrices -> 48 uint4 = 192 dw
    uint4 w1[2][8], wi2[2][8], wh2[2][8];
    #pragma unroll
    for (int rr = 0; rr < 2; ++rr) {
        const uint4* p1 = (const uint4*)(w1p  + (size_t)(gr0 + rr) * HH + 64 * s);
        const uint4* p2 = (const uint4*)(wi2p + (size_t)(gr0 + rr) * HH + 64 * s);
        const uint4* p3 = (const uint4*)(wh2p + (size_t)(gr0 + rr) * HH + 64 * s);
        #pragma unroll
        for (int k = 0; k < 8; ++k) {
            w1[rr][k] = p1[k]; wi2[rr][k] = p2[k]; wh2[rr][k] = p3[k];
        }
    }
    // Pin: opaque to the optimizer -> rematerializing re-load illegal.
    #pragma unroll
    for (int rr = 0; rr < 2; ++rr) {
        #pragma unroll
        for (int k = 0; k < 8; ++k) {
            asm volatile("" : "+v"(w1[rr][k].x),  "+v"(w1[rr][k].y),  "+v"(w1[rr][k].z),  "+v"(w1[rr][k].w));
            asm volatile("" : "+v"(wi2[rr][k].x), "+v"(wi2[rr][k].y), "+v"(wi2[rr][k].z), "+v"(wi2[rr][k].w));
            asm volatile("" : "+v"(wh2[rr][k].x), "+v"(wh2[rr][k].y), "+v"(wh2[rr][k].z), "+v"(wh2[rr][k].w));
        }
    }
    const float wi1v0 = wi1p[gr0],     b1v0 = b1p[gr0],     b2v0 = b2p[gr0];
    const float wi1v1 = wi1p[gr0 + 1], b1v1 = b1p[gr0 + 1], b2v1 = b2p[gr0 + 1];

    xs[tid] = x[(size_t)b * TT + tid];
    if (tid < HH) {
        h1h[0][tid] = 0; h1h[1][tid] = 0;
        c1h[0][tid] = 0; c1h[1][tid] = 0;
        h2h[0][tid] = 0; h2h[1][tid] = 0;
    }
    float c1reg = 0.f, c2reg = 0.f;   // cell state lives on half==0 lanes
    __syncthreads();

    float* outp = h2a + (size_t)b * HH + h;

    // ---- prologue u=0: layer-1 only, h1(prev)=0 -> gates are scalar ----
    {
        float g0 = fmaf(xs[0], wi1v0, b1v0);
        float g1 = fmaf(xs[0], wi1v1, b1v1);
        float e0 = act(g0, hB);                 // A: sig(i) ; B: tanh(g)
        float e1 = act(g1, false);              // A: sig(f) ; B: sig(o)
        float peer = dppmov<0x4E>(e0);          // A <- tanh(g)
        float cn1 = fmaf(e1, c1reg, e0 * peer); // valid on A
        c1reg = hB ? c1reg : cn1;
        float cnp = dppmov<0x4E>(cn1);          // B <- cn
        float hn1 = e1 * act(cnp, true);        // valid on B
        if (s == 0) {
            if (hB) h1h[1][h] = f16b(hn1);
            else    c1h[1][h] = f16b(cn1);
        }
    }
    STEP_BARRIER();

    // ---- main: u = 1 .. TT-1 (layer-1 at t=u, layer-2 at t=u-1) ----
    for (int u = 1; u < TT; ++u) {
        const int p = u & 1, q = p ^ 1;
        const float xv = xs[u];

        uint4 sv[8];
        // layer-1 dots: h1h[p] = h1(u-1)
        const uint4* hp = (const uint4*)&h1h[p][64 * s];
        #pragma unroll
        for (int k = 0; k < 8; ++k) sv[k] = hp[k];
        float a0 = 0.f, a1 = 0.f;
        dot32(a0, w1[0], sv);
        dot32(a1, w1[1], sv);
        // layer-2 dots: c1h[p] = c1(u-1), h2h[p] = h2(u-2)
        const uint4* cp = (const uint4*)&c1h[p][64 * s];
        #pragma unroll
        for (int k = 0; k < 8; ++k) sv[k] = cp[k];
        float d0 = 0.f, d1 = 0.f;
        dot32(d0, wi2[0], sv);
        dot32(d1, wi2[1], sv);
        const uint4* gp = (const uint4*)&h2h[p][64 * s];
        #pragma unroll
        for (int k = 0; k < 8; ++k) sv[k] = gp[k];
        dot32(d0, wh2[0], sv);
        dot32(d1, wh2[1], sv);

        // col-half reduce (pure DPP)
        a0 = dppadd<0xB1>(a0); a1 = dppadd<0xB1>(a1);
        d0 = dppadd<0xB1>(d0); d1 = dppadd<0xB1>(d1);

        // ---- cell-1 (t=u) ----
        float g0 = a0 + fmaf(xv, wi1v0, b1v0);
        float g1 = a1 + fmaf(xv, wi1v1, b1v1);
        float e0 = act(g0, hB);
        float e1 = act(g1, false);
        float peer = dppmov<0x4E>(e0);
        float cn1 = fmaf(e1, c1reg, e0 * peer);
        c1reg = hB ? c1reg : cn1;
        float cnp1 = dppmov<0x4E>(cn1);
        float hn1 = e1 * act(cnp1, true);

        // ---- cell-2 (t=u-1) ----
        float f0 = d0 + b2v0;
        float f1 = d1 + b2v1;
        float u0 = act(f0, hB);
        float u1 = act(f1, false);
        float peer2 = dppmov<0x4E>(u0);
        float cn2 = fmaf(u1, c2reg, u0 * peer2);
        c2reg = hB ? c2reg : cn2;
        float cnp2 = dppmov<0x4E>(cn2);
        float hn2 = u1 * act(cnp2, true);

        if (s == 0) {
            if (hB) {
                h1h[q][h] = f16b(hn1);
                h2h[q][h] = f16b(hn2);
                outp[(size_t)(u - 1) * (BB * HH)] = hn2;
            } else {
                c1h[q][h] = f16b(cn1);
            }
        }
        STEP_BARRIER();
    }

    // ---- epilogue u=TT: layer-2 only (t = TT-1), buffers p = TT&1 = 0 ----
    {
        uint4 sv[8];
        const uint4* cp = (const uint4*)&c1h[0][64 * s];
        #pragma unroll
        for (int k = 0; k < 8; ++k) sv[k] = cp[k];
        float d0 = 0.f, d1 = 0.f;
        dot32(d0, wi2[0], sv);
        dot32(d1, wi2[1], sv);
        const uint4* gp = (const uint4*)&h2h[0][64 * s];
        #pragma unroll
        for (int k = 0; k < 8; ++k) sv[k] = gp[k];
        dot32(d0, wh2[0], sv);
        dot32(d1, wh2[1], sv);
        d0 = dppadd<0xB1>(d0); d1 = dppadd<0xB1>(d1);
        float f0 = d0 + b2v0;
        float f1 = d1 + b2v1;
        float u0 = act(f0, hB);
        float u1 = act(f1, false);
        float peer2 = dppmov<0x4E>(u0);
        float cn2 = fmaf(u1, c2reg, u0 * peer2);
        float cnp2 = dppmov<0x4E>(cn2);
        float hn2 = u1 * act(cnp2, true);
        if (hB && s == 0) outp[(size_t)(TT - 1) * (BB * HH)] = hn2;
    }
}

// K2: d_old[t,b] = h2[t,b,:].wt_old ; d_h[t,b] = h2[t,b,:].wt_h  (unchanged)
__global__ __launch_bounds__(256) void k2_dots(
    const float* __restrict__ h2a, const float* __restrict__ w_t,
    float* __restrict__ dold, float* __restrict__ dh)
{
    const int lane = threadIdx.x & 63;
    const int wave = blockIdx.x * (blockDim.x >> 6) + (threadIdx.x >> 6);
    const int nw = gridDim.x * (blockDim.x >> 6);
    const float wh0 = w_t[lane],       wh1 = w_t[64 + lane];
    const float wo0 = w_t[128 + lane], wo1 = w_t[192 + lane];
    for (int row = wave; row < TT * BB; row += nw) {
        const float* p = h2a + (size_t)row * HH;
        float v0 = p[lane], v1 = p[64 + lane];
        float po = v0 * wo0 + v1 * wo1;
        float ph = v0 * wh0 + v1 * wh1;
        #pragma unroll
        for (int off = 32; off; off >>= 1) {
            po += __shfl_xor(po, off);
            ph += __shfl_xor(ph, off);
        }
        if (lane == 0) { dold[row] = po; dh[row] = ph; }
    }
}

// K3: per-t global softmax stats over valid (j,b): m[t], s[t]  (unchanged)
__global__ __launch_bounds__(256) void k3_stats(
    const float* __restrict__ dold, const float* __restrict__ dh,
    float* __restrict__ mt, float* __restrict__ st)
{
    const int t = blockIdx.x;
    const int tid = threadIdx.x;
    const int cnt = (min(t, WW) + 1) * BB;
    const int jstart = max(t - (WW + 1), -1);

    float m = -INFINITY;
    for (int idx = tid; idx < cnt; idx += 256) {
        int jj = idx >> 7, b = idx & 127;
        int j = jstart + jj;
        float sc = dh[t * BB + b] + (j >= 0 ? dold[j * BB + b] : 0.f);
        m = fmaxf(m, sc);
    }
    #pragma unroll
    for (int off = 32; off; off >>= 1) m = fmaxf(m, __shfl_xor(m, off));
    __shared__ float rbuf[4];
    int wv = tid >> 6, ln = tid & 63;
    if (ln == 0) rbuf[wv] = m;
    __syncthreads();
    m = fmaxf(fmaxf(rbuf[0], rbuf[1]), fmaxf(rbuf[2], rbuf[3]));

    float s = 0.f;
    for (int idx = tid; idx < cnt; idx += 256) {
        int jj = idx >> 7, b = idx & 127;
        int j = jstart + jj;
        float sc = dh[t * BB + b] + (j >= 0 ? dold[j * BB + b] : 0.f);
        s += __expf(sc - m);
    }
    #pragma unroll
    for (int off = 32; off; off >>= 1) s += __shfl_xor(s, off);
    __shared__ float sbuf[4];
    if (ln == 0) sbuf[wv] = s;
    __syncthreads();
    if (tid == 0) { mt[t] = m; st[t] = sbuf[0] + sbuf[1] + sbuf[2] + sbuf[3]; }
}

// K45: fused attention + FC. grid (TT/8, BB), block 256.  (unchanged)
__global__ __launch_bounds__(256) void k45_attn_fc(
    const float* __restrict__ h2a,
    const float* __restrict__ dold, const float* __restrict__ dh,
    const float* __restrict__ mt, const float* __restrict__ st,
    const float* __restrict__ fcWT, const float* __restrict__ fcb,
    float* __restrict__ out)
{
    const int t0 = blockIdx.x * 8;
    const int b  = blockIdx.y;
    const int tid = threadIdx.x;

    __shared__ float hbuf[41][HH];     // rows t0-33 .. t0+7
    __shared__ float wjs[8][36];
    __shared__ float ytile[8][HH];

    for (int i = tid; i < 41 * 32; i += 256) {
        int r = i >> 5, q4 = i & 31;
        int t = t0 - 33 + r;
        float4 v = make_float4(0.f, 0.f, 0.f, 0.f);
        if (t >= 0)
            v = *(const float4*)(h2a + (size_t)t * (BB * HH) + (size_t)b * HH + q4 * 4);
        *(float4*)&hbuf[r][q4 * 4] = v;
    }
    for (int i = tid; i < 8 * 33; i += 256) {
        int tt = i / 33, ss = i % 33;
        int t = t0 + tt, j = t - 33 + ss;
        float w = 0.f;
        if (j >= 0)
            w = __expf(dold[j * BB + b] + dh[t * BB + b] - mt[t]) / st[t];
        wjs[tt][ss] = w;
    }
    __syncthreads();

    {
        const int tq = tid >> 5;
        const int hq = (tid & 31) * 4;
        float4 acc = *(const float4*)&hbuf[tq + 33][hq];   // h2[t]
        #pragma unroll 11
        for (int ss = 0; ss < 33; ++ss) {
            float w = wjs[tq][ss];
            float4 hb = *(const float4*)&hbuf[tq + ss][hq];
            acc.x = fmaf(w, hb.x, acc.x);
            acc.y = fmaf(w, hb.y, acc.y);
            acc.z = fmaf(w, hb.z, acc.z);
            acc.w = fmaf(w, hb.w, acc.w);
        }
        *(float4*)&ytile[tq][hq] = acc;
    }
    __syncthreads();

    {
        const int c  = tid & 127;
        const int th = tid >> 7;
        float acc[4];
        const float bias = fcb[c];
        #pragma unroll
        for (int i = 0; i < 4; ++i) acc[i] = bias;
        for (int hh = 0; hh < HH; ++hh) {
            float w = fcWT[hh * CC + c];
            #pragma unroll
            for (int i = 0; i < 4; ++i)
                acc[i] = fmaf(ytile[th * 4 + i][hh], w, acc[i]);
        }
        #pragma unroll
        for (int i = 0; i < 4; ++i) {
            int t = t0 + th * 4 + i;
            out[(size_t)b * (TT * CC) + (size_t)t * CC + c] = acc[i];
        }
    }
}

extern "C" void kernel_launch(void* const* d_in, const int* in_sizes, int n_in,
                              void* d_out, int out_size, void* d_ws, size_t ws_size,
                              hipStream_t stream)
{
    const float* x    = (const float*)d_in[0];
    const float* Wih1 = (const float*)d_in[1];
    const float* Whh1 = (const float*)d_in[2];
    const float* bih1 = (const float*)d_in[3];
    const float* bhh1 = (const float*)d_in[4];
    const float* Wih2 = (const float*)d_in[5];
    const float* Whh2 = (const float*)d_in[6];
    const float* bih2 = (const float*)d_in[7];
    const float* bhh2 = (const float*)d_in[8];
    const float* w_t  = (const float*)d_in[9];
    const float* fcW  = (const float*)d_in[10];
    const float* fcb  = (const float*)d_in[11];
    float* out = (float*)d_out;

    float* ws   = (float*)d_ws;
    float* fcWT = ws + OFF_FCWT;
    unsigned short* w1p  = (unsigned short*)(ws + OFF_W1P);
    unsigned short* wi2p = (unsigned short*)(ws + OFF_WI2P);
    unsigned short* wh2p = (unsigned short*)(ws + OFF_WH2P);
    float* b1pp = ws + OFF_B1P;
    float* wi1p = ws + OFF_WI1P;
    float* b2pp = ws + OFF_B2P;
    float* h2a  = ws + OFF_H2A;
    float* dold = ws + OFF_DOLD;
    float* dh   = ws + OFF_DH;
    float* mt   = ws + OFF_MT;
    float* st   = ws + OFF_ST;

    k0_prep<<<dim3((G4 * HH + 255) / 256), dim3(256), 0, stream>>>(
        Whh1, Wih2, Whh2, fcW, Wih1, bih1, bhh1, bih2, bhh2,
        fcWT, w1p, wi2p, wh2p, b1pp, wi1p, b2pp);

    k1_lstm<<<dim3(BB), dim3(512), 0, stream>>>(
        x, b1pp, wi1p, b2pp, w1p, wi2p, wh2p, h2a);

    k2_dots<<<dim3(256), dim3(256), 0, stream>>>(h2a, w_t, dold, dh);

    k3_stats<<<dim3(TT), dim3(256), 0, stream>>>(dold, dh, mt, st);

    k45_attn_fc<<<dim3(TT / 8, BB), dim3(256), 0, stream>>>(
        h2a, dold, dh, mt, st, fcWT, fcb, out);
}